// Round 17
// baseline (148.390 us; speedup 1.0000x reference)
//
#include <hip/hip_runtime.h>
#include <hip/hip_bf16.h>

typedef __bf16 bf16_t;
typedef __bf16 bf16x4 __attribute__((ext_vector_type(4)));
typedef __bf16 bf16x8 __attribute__((ext_vector_type(8)));
typedef float f32x4 __attribute__((ext_vector_type(4)));
typedef unsigned int u32;
typedef u32 u32x4 __attribute__((ext_vector_type(4)));

constexpr int E  = 1024;
constexpr int NH = 16;
constexpr int HD = 64;
constexpr int NB = 2;
constexpr int GS = 48;          // spatial side
constexpr int L  = GS * GS;     // 2304 tokens per batch
constexpr int T  = NB * L;      // 4608 tokens
constexpr int BH = NB * NH;     // 32 batch*head

static __device__ __forceinline__ float max3f(float a, float b, float c) {
    return fmaxf(fmaxf(a, b), c);   // clang fuses to v_max3_f32
}

static __device__ __forceinline__ void gload16(const void* g, void* l) {
    __builtin_amdgcn_global_load_lds(
        (const __attribute__((address_space(1))) unsigned int*)g,
        (__attribute__((address_space(3))) unsigned int*)l, 16, 0, 0);
}

// cross-half reduces via permlane-swap BUILTINS (hazards handled by compiler)
static __device__ __forceinline__ float redmax16(float x) {
    u32 a = __builtin_bit_cast(u32, x);
    auto r = __builtin_amdgcn_permlane16_swap(a, a, false, false);
    return fmaxf(__builtin_bit_cast(float, r[0]), __builtin_bit_cast(float, r[1]));
}
static __device__ __forceinline__ float redmax32(float x) {
    u32 a = __builtin_bit_cast(u32, x);
    auto r = __builtin_amdgcn_permlane32_swap(a, a, false, false);
    return fmaxf(__builtin_bit_cast(float, r[0]), __builtin_bit_cast(float, r[1]));
}
// single-instruction packed f32->bf16 (R7-proven; compiler scalar casts are multi-op)
static __device__ __forceinline__ u32 cvtpk(float lo, float hi) {
    u32 r;
    asm("v_cvt_pk_bf16_f32 %0, %1, %2" : "=v"(r) : "v"(lo), "v"(hi));
    return r;
}
// raw v_exp_f32 (2^x) via compiler-known builtin — no libcall range checks
static __device__ __forceinline__ float exp2fast(float x) {
    return __builtin_amdgcn_exp2f(x);
}

// ------- prep: cast x and Wq/Wk/Wv/Wo to bf16 (+ xpos tables in block 0) -------
__global__ __launch_bounds__(256)
void prep_kernel(const float* __restrict__ x,
                 const float* __restrict__ Wq, const float* __restrict__ Wk,
                 const float* __restrict__ Wv, const float* __restrict__ Wo,
                 bf16_t* __restrict__ x_b,
                 bf16_t* __restrict__ Wq_b, bf16_t* __restrict__ Wk_b,
                 bf16_t* __restrict__ Wv_b, bf16_t* __restrict__ Wo_b,
                 float* __restrict__ tabs)
{
    if (blockIdx.x == 0) {
        #pragma unroll
        for (int j = 0; j < 3; ++j) {
            int i = threadIdx.x + 256 * j;           // 0..767
            int p = i >> 4, jj = i & 15;
            float sv = (2.0f * (float)jj + 12.8f) / 44.8f;
            float pw = ((float)p - 24.0f) / 512.0f;
            float scale = powf(sv, pw);
            float inv_freq = powf(10000.0f, -(float)jj / 16.0f);
            float ang = (float)p * inv_freq;
            float s = sinf(ang), c = cosf(ang);
            tabs[0 * 768 + i] = c * scale;   // q: downscale=False
            tabs[1 * 768 + i] = s * scale;
            tabs[2 * 768 + i] = c / scale;   // k: downscale=True
            tabs[3 * 768 + i] = s / scale;
        }
    }
    const int gid = blockIdx.x * 256 + threadIdx.x;      // 0 .. T*E/4-1
    {
        f32x4 v = *reinterpret_cast<const f32x4*>(x + (size_t)gid * 4);
        bf16x4 o;
        o[0] = (bf16_t)v[0]; o[1] = (bf16_t)v[1]; o[2] = (bf16_t)v[2]; o[3] = (bf16_t)v[3];
        *reinterpret_cast<bf16x4*>(x_b + (size_t)gid * 4) = o;
    }
    if (blockIdx.x < 1024) {
        const float* srcs[4] = {Wq, Wk, Wv, Wo};
        bf16_t* dsts[4] = {Wq_b, Wk_b, Wv_b, Wo_b};
        #pragma unroll
        for (int wsel = 0; wsel < 4; ++wsel) {
            f32x4 v = *reinterpret_cast<const f32x4*>(srcs[wsel] + (size_t)gid * 4);
            bf16x4 o;
            o[0] = (bf16_t)v[0]; o[1] = (bf16_t)v[1]; o[2] = (bf16_t)v[2]; o[3] = (bf16_t)v[3];
            *reinterpret_cast<bf16x4*>(dsts[wsel] + (size_t)gid * 4) = o;
        }
    }
}

// ---------------- fused QKV GEMM (z = 0:Q+xpos, 1:K+xpos, 2:V transposed) ----------
// SM[0]=As, SM[1]=Bs during K-loop; reused as C-stage for coalesced Q/K stores.
__global__ __launch_bounds__(256, 3)
void qkv_gemm_kernel(const bf16_t* __restrict__ Ax,
                     const bf16_t* __restrict__ Wqb, const bf16_t* __restrict__ Wkb,
                     const bf16_t* __restrict__ Wvb,
                     const float* __restrict__ bq, const float* __restrict__ bk,
                     const float* __restrict__ bv,
                     bf16_t* __restrict__ q_ws, bf16_t* __restrict__ k_ws,
                     bf16_t* __restrict__ vT_ws, const float* __restrict__ tabs)
{
    __shared__ bf16_t SM[2][128 * 64];
    const int z = blockIdx.z;
    const bf16_t* Wb   = (z == 0) ? Wqb : (z == 1) ? Wkb : Wvb;
    const float*  bias = (z == 0) ? bq  : (z == 1) ? bk  : bv;

    const int tid = threadIdx.x;
    const int lane = tid & 63;
    const int wv = tid >> 6;
    const int wm = wv >> 1, wn = wv & 1;
    const int lr = lane & 15, lg = lane >> 4;
    const int bm = blockIdx.x, bn = blockIdx.y;

    f32x4 acc[4][4] = {};

    for (int kt = 0; kt < E / 64; ++kt) {
        const int k0 = kt * 64;
        __syncthreads();
        const bf16_t* Abase = Ax + (size_t)(bm * 128) * E + k0;
        const bf16_t* Wbase = Wb + (size_t)(bn * 128) * E + k0;
        #pragma unroll
        for (int it = 0; it < 4; ++it) {
            int s = it * 256 + tid;
            int r = s >> 3, c = s & 7;
            const int off = (c ^ (r & 7)) * 8;
            gload16(Abase + (size_t)r * E + off, (char*)SM[0] + it * 4096 + wv * 1024);
            gload16(Wbase + (size_t)r * E + off, (char*)SM[1] + it * 4096 + wv * 1024);
        }
        __syncthreads();
        #pragma unroll
        for (int kk = 0; kk < 2; ++kk) {
            bf16x8 af[4], bfr[4];
            #pragma unroll
            for (int m = 0; m < 4; ++m) {
                int row = wm * 64 + m * 16 + lr;
                af[m] = *reinterpret_cast<const bf16x8*>(&SM[0][row * 64 + (((kk * 4 + lg) ^ (row & 7)) * 8)]);
            }
            #pragma unroll
            for (int n = 0; n < 4; ++n) {
                int row = wn * 64 + n * 16 + lr;
                bfr[n] = *reinterpret_cast<const bf16x8*>(&SM[1][row * 64 + (((kk * 4 + lg) ^ (row & 7)) * 8)]);
            }
            #pragma unroll
            for (int m = 0; m < 4; ++m)
                #pragma unroll
                for (int n = 0; n < 4; ++n)
                    acc[m][n] = __builtin_amdgcn_mfma_f32_16x16x32_bf16(af[m], bfr[n], acc[m][n], 0, 0, 0);
        }
    }

    if (z < 2) {
        const float* cs_t = tabs + (z == 0 ? 0 : 1536);
        const float* ss_t = tabs + (z == 0 ? 768 : 2304);
        bf16_t* dst = (z == 0) ? q_ws : k_ws;
        // Q additionally scaled by log2(e) so attn softmax can use exp2 directly
        const float qscale = 0.125f * 1.44269504088896f;
        __syncthreads();   // all waves done reading SM as A/B
        #pragma unroll
        for (int m = 0; m < 4; ++m) {
            #pragma unroll
            for (int n = 0; n < 4; ++n) {
                const int col = bn * 128 + wn * 64 + n * 16 + lr;
                const float bvv = bias[col];
                const int d = col & 63;
                const int j = (d & 31) >> 1, half = d >> 5, odd = d & 1;
                #pragma unroll
                for (int r = 0; r < 4; ++r) {
                    const int rowl = wm * 64 + m * 16 + lg * 4 + r;
                    const int rowg = bm * 128 + rowl;
                    const int nb = rowg / L, ll = rowg - nb * L;
                    const int y = ll / GS, x = ll - y * GS;
                    const int pos = half ? y : x;
                    float v = acc[m][n][r] + bvv;
                    if (z == 0) v *= qscale;
                    float o = __shfl_xor(v, 1);
                    float cs = cs_t[pos * 16 + j], ss = ss_t[pos * 16 + j];
                    float res = odd ? (v * cs + o * ss) : (v * cs - o * ss);
                    SM[wn][rowl * 64 + n * 16 + lr] = (bf16_t)res;
                }
            }
        }
        __syncthreads();
        const int row = tid >> 1;
        const int off32 = (tid & 1) * 32;
        const int rowg = bm * 128 + row;
        const int nb2 = (rowg >= L) ? 1 : 0;
        const int ll = rowg - nb2 * L;
        #pragma unroll
        for (int phase = 0; phase < 2; ++phase) {
            const int head = bn * 2 + phase;
            bf16_t* gdst = dst + ((size_t)(nb2 * NH + head) * L + ll) * HD + off32;
            const bf16_t* src = &SM[phase][row * 64 + off32];
            #pragma unroll
            for (int c = 0; c < 4; ++c)
                *reinterpret_cast<bf16x8*>(gdst + c * 8) =
                    *reinterpret_cast<const bf16x8*>(src + c * 8);
        }
    } else {
        #pragma unroll
        for (int m = 0; m < 4; ++m) {
            const int rowg0 = bm * 128 + wm * 64 + m * 16 + lg * 4;
            const int nb = rowg0 / L, ll0 = rowg0 - nb * L;
            #pragma unroll
            for (int n = 0; n < 4; ++n) {
                const int col = bn * 128 + wn * 64 + n * 16 + lr;
                const float bvv = bias[col];
                const int head = col >> 6, d = col & 63;
                bf16x4 pk;
                #pragma unroll
                for (int r = 0; r < 4; ++r) pk[r] = (bf16_t)(acc[m][n][r] + bvv);
                *reinterpret_cast<bf16x4*>(&vT_ws[((size_t)(nb * NH + head) * HD + d) * L + ll0]) = pk;
            }
        }
    }
}

// ---------------- flash attention: 512 threads = 8 waves/block, 32KB LDS ----------
// 4 blocks/CU = 128KB LDS, 32 waves/CU (full wave cap). Wave owns 16 queries.
// grid 576 (1D); XCD swizzle: 576 = 8*72, 72 = 4 bh -> 2.3MB K+V per XCD (L2-fit).
__global__ __launch_bounds__(512, 8)
void attn_kernel(const bf16_t* __restrict__ q_ws, const bf16_t* __restrict__ k_ws,
                 const bf16_t* __restrict__ vT_ws, bf16_t* __restrict__ attn_out)
{
    __shared__ bf16_t K_lds[2][64 * 64];   // [l][d], chunk-XOR-swizzled rows (128B)
    __shared__ bf16_t V_lds[2][64 * 64];   // [d][l], chunk-XOR-swizzled rows (128B)
    const int tid = threadIdx.x;
    const int lane = tid & 63, w = tid >> 6;         // w in [0,8)
    const int lr = lane & 15, lg = lane >> 4;
    const int n = blockIdx.x;
    const int swz = (n & 7) * 72 + (n >> 3);
    const int bh = swz / 18;
    const int q0 = (swz - bh * 18) * 128 + w * 16;
    const int nb = bh >> 4, head = bh & 15;

    const bf16_t* qb = q_ws + (size_t)bh * L * HD;
    const bf16_t* kb = k_ws + (size_t)bh * L * HD;
    const bf16_t* vb = vT_ws + (size_t)bh * HD * L;

    // staging: 512 lanes cover 512 16B-chunks of each 8KB tile (1 chunk each)
    const int s0 = w * 64 + lane;                    // 0..511
    const int r0 = s0 >> 3, c0 = s0 & 7;
    const int cx = c0 ^ (r0 & 7);
    const bf16_t* kst = kb + r0 * HD + cx * 8;
    const bf16_t* vst = vb + (size_t)r0 * L + cx * 8;

    bf16x8 qf[2];
    qf[0] = *reinterpret_cast<const bf16x8*>(qb + (size_t)(q0 + lr) * HD + lg * 8);
    qf[1] = *reinterpret_cast<const bf16x8*>(qb + (size_t)(q0 + lr) * HD + 32 + lg * 8);

    // ones A-fragment: l_acc = mfma(ones, P, l_acc) accumulates column sums of P
    bf16x8 ones;
    #pragma unroll
    for (int i = 0; i < 8; ++i) ones[i] = (bf16_t)1.0f;

    // hoisted lane-constant LDS element offsets (independent of kt/BUF)
    int koffA[4], koffB[4], voff[2][4];
    #pragma unroll
    for (int ct = 0; ct < 4; ++ct) {
        const int row = ct * 16 + lr;
        koffA[ct] = row * 64 + ((lg ^ (lr & 7)) * 8);
        koffB[ct] = row * 64 + (((4 + lg) ^ (lr & 7)) * 8);
    }
    #pragma unroll
    for (int kk = 0; kk < 2; ++kk)
        #pragma unroll
        for (int dt = 0; dt < 4; ++dt)
            voff[kk][dt] = (dt * 16 + lr) * 64 + (((kk * 4 + lg) ^ (lr & 7)) * 8);

    f32x4 o_acc[4] = {};
    f32x4 l_acc = {};
    float m_run = -1e30f;

    // stage tile 0 -> buf 0 (one K chunk + one V chunk per lane)
    gload16(kst, (char*)K_lds[0] + w * 1024);
    gload16(vst, (char*)V_lds[0] + w * 1024);
    __syncthreads();

    // incremental prefetch pointers (advance by 2 tiles per loop iteration)
    const bf16_t* kpA = kst + 4096;   const bf16_t* vpA = vst + 64;    // odd tiles
    const bf16_t* kpB = kst + 8192;   const bf16_t* vpB = vst + 128;   // even tiles

    constexpr int NT = L / 64;   // 36 (even)

#define ATTN_COMPUTE(BUF)                                                              \
    {                                                                                  \
        f32x4 s[4];                                                                    \
        __builtin_amdgcn_s_setprio(1);                                                 \
        _Pragma("unroll")                                                              \
        for (int ct = 0; ct < 4; ++ct) {                                               \
            bf16x8 kf0 = *reinterpret_cast<const bf16x8*>(&K_lds[BUF][koffA[ct]]);     \
            bf16x8 kf1 = *reinterpret_cast<const bf16x8*>(&K_lds[BUF][koffB[ct]]);     \
            f32x4 t = {};                                                              \
            t = __builtin_amdgcn_mfma_f32_16x16x32_bf16(kf0, qf[0], t, 0, 0, 0);       \
            t = __builtin_amdgcn_mfma_f32_16x16x32_bf16(kf1, qf[1], t, 0, 0, 0);       \
            s[ct] = t;                                                                 \
        }                                                                              \
        __builtin_amdgcn_s_setprio(0);                                                 \
        float m0 = max3f(s[0][0], s[0][1], s[0][2]);                                   \
        float m1 = max3f(s[0][3], s[1][0], s[1][1]);                                   \
        float m2 = max3f(s[1][2], s[1][3], s[2][0]);                                   \
        float m3 = max3f(s[2][1], s[2][2], s[2][3]);                                   \
        float m4 = max3f(s[3][0], s[3][1], s[3][2]);                                   \
        float mt = fmaxf(max3f(m0, m1, m2), max3f(m3, m4, s[3][3]));                   \
        mt = redmax16(mt);                                                             \
        mt = redmax32(mt);                                                             \
        if (!__all(mt <= m_run + 11.54f)) {                                            \
            const float mn = fmaxf(m_run, mt);                                         \
            const float al = exp2fast(m_run - mn);                                     \
            m_run = mn;                                                                \
            l_acc *= al;                                                               \
            _Pragma("unroll")                                                          \
            for (int dt = 0; dt < 4; ++dt) o_acc[dt] *= al;                            \
        }                                                                              \
        _Pragma("unroll")                                                              \
        for (int ct = 0; ct < 4; ++ct) {                                               \
            s[ct][0] = exp2fast(s[ct][0] - m_run); s[ct][1] = exp2fast(s[ct][1] - m_run); \
            s[ct][2] = exp2fast(s[ct][2] - m_run); s[ct][3] = exp2fast(s[ct][3] - m_run); \
        }                                                                              \
        u32 c01[4], c23[4];                                                            \
        _Pragma("unroll")                                                              \
        for (int ct = 0; ct < 4; ++ct) {                                               \
            c01[ct] = cvtpk(s[ct][0], s[ct][1]);                                       \
            c23[ct] = cvtpk(s[ct][2], s[ct][3]);                                       \
        }                                                                              \
        __builtin_amdgcn_s_setprio(1);                                                 \
        _Pragma("unroll")                                                              \
        for (int kk = 0; kk < 2; ++kk) {                                               \
            auto p1 = __builtin_amdgcn_permlane32_swap(c01[kk*2], c01[kk*2+1], false, false); \
            auto p2 = __builtin_amdgcn_permlane16_swap(p1[0], p1[1], false, false);    \
            auto p3 = __builtin_amdgcn_permlane32_swap(c23[kk*2], c23[kk*2+1], false, false); \
            auto p4 = __builtin_amdgcn_permlane16_swap(p3[0], p3[1], false, false);    \
            u32x4 paw;                                                                 \
            paw[0] = p2[0]; paw[1] = p4[0]; paw[2] = p2[1]; paw[3] = p4[1];            \
            bf16x8 pa = __builtin_bit_cast(bf16x8, paw);                               \
            l_acc = __builtin_amdgcn_mfma_f32_16x16x32_bf16(ones, pa, l_acc, 0, 0, 0); \
            _Pragma("unroll")                                                          \
            for (int dt = 0; dt < 4; ++dt) {                                           \
                bf16x8 vfr = *reinterpret_cast<const bf16x8*>(&V_lds[BUF][voff[kk][dt]]); \
                o_acc[dt] = __builtin_amdgcn_mfma_f32_16x16x32_bf16(vfr, pa, o_acc[dt], 0, 0, 0); \
            }                                                                          \
        }                                                                              \
        __builtin_amdgcn_s_setprio(0);                                                 \
        __syncthreads();                                                               \
    }

    for (int it = 0; it < NT / 2; ++it) {
        // even tile 2*it: compute buf0; prefetch tile 2*it+1 -> buf1 (always valid)
        gload16(kpA, (char*)K_lds[1] + w * 1024);
        gload16(vpA, (char*)V_lds[1] + w * 1024);
        kpA += 8192; vpA += 128;
        ATTN_COMPUTE(0)
        // odd tile 2*it+1: compute buf1; prefetch tile 2*it+2 -> buf0 (if exists)
        if (it < NT / 2 - 1) {
            gload16(kpB, (char*)K_lds[0] + w * 1024);
            gload16(vpB, (char*)V_lds[0] + w * 1024);
            kpB += 8192; vpB += 128;
        }
        ATTN_COMPUTE(1)
    }
#undef ATTN_COMPUTE

    const float inv = 1.0f / l_acc[0];
    #pragma unroll
    for (int dt = 0; dt < 4; ++dt) {
        bf16x4 o;
        #pragma unroll
        for (int r = 0; r < 4; ++r) o[r] = (bf16_t)(o_acc[dt][r] * inv);
        *reinterpret_cast<bf16x4*>(
            &attn_out[(size_t)(nb * L + q0 + lr) * E + head * HD + dt * 16 + lg * 4]) = o;
    }
}

// ---------------- output projection GEMM: 128x64 tiles (2.25 blocks/CU) -----------
__global__ __launch_bounds__(256, 4)
void out_gemm_kernel(const bf16_t* __restrict__ A, const bf16_t* __restrict__ Wb,
                     const float* __restrict__ bias, float* __restrict__ outp)
{
    __shared__ bf16_t As[128 * 64];
    __shared__ bf16_t Bs[64 * 64];
    const int tid = threadIdx.x;
    const int lane = tid & 63;
    const int wv = tid >> 6;
    const int wm = wv >> 1, wn = wv & 1;
    const int lr = lane & 15, lg = lane >> 4;
    const int bm = blockIdx.x, bn = blockIdx.y;

    f32x4 acc[4][2] = {};

    for (int kt = 0; kt < E / 64; ++kt) {
        const int k0 = kt * 64;
        __syncthreads();
        const bf16_t* Abase = A  + (size_t)(bm * 128) * E + k0;
        const bf16_t* Wbase = Wb + (size_t)(bn * 64) * E + k0;
        #pragma unroll
        for (int it = 0; it < 4; ++it) {
            int s = it * 256 + tid;
            int r = s >> 3, c = s & 7;
            const int off = (c ^ (r & 7)) * 8;
            gload16(Abase + (size_t)r * E + off, (char*)As + it * 4096 + wv * 1024);
        }
        #pragma unroll
        for (int it = 0; it < 2; ++it) {
            int s = it * 256 + tid;
            int r = s >> 3, c = s & 7;
            const int off = (c ^ (r & 7)) * 8;
            gload16(Wbase + (size_t)r * E + off, (char*)Bs + it * 4096 + wv * 1024);
        }
        __syncthreads();
        #pragma unroll
        for (int kk = 0; kk < 2; ++kk) {
            bf16x8 af[4], bfr[2];
            #pragma unroll
            for (int m = 0; m < 4; ++m) {
                int row = wm * 64 + m * 16 + lr;
                af[m] = *reinterpret_cast<const bf16x8*>(&As[row * 64 + (((kk * 4 + lg) ^ (row & 7)) * 8)]);
            }
            #pragma unroll
            for (int n = 0; n < 2; ++n) {
                int row = wn * 32 + n * 16 + lr;
                bfr[n] = *reinterpret_cast<const bf16x8*>(&Bs[row * 64 + (((kk * 4 + lg) ^ (row & 7)) * 8)]);
            }
            #pragma unroll
            for (int m = 0; m < 4; ++m)
                #pragma unroll
                for (int n = 0; n < 2; ++n)
                    acc[m][n] = __builtin_amdgcn_mfma_f32_16x16x32_bf16(af[m], bfr[n], acc[m][n], 0, 0, 0);
        }
    }

    #pragma unroll
    for (int m = 0; m < 4; ++m) {
        #pragma unroll
        for (int n = 0; n < 2; ++n) {
            const int col = bn * 64 + wn * 32 + n * 16 + lr;
            const float bvv = bias[col];
            #pragma unroll
            for (int r = 0; r < 4; ++r) {
                const int rowg = bm * 128 + wm * 64 + m * 16 + lg * 4 + r;
                outp[(size_t)rowg * E + col] = acc[m][n][r] + bvv;
            }
        }
    }
}

// ---------------- launch ----------------
extern "C" void kernel_launch(void* const* d_in, const int* in_sizes, int n_in,
                              void* d_out, int out_size, void* d_ws, size_t ws_size,
                              hipStream_t stream)
{
    const float* query = (const float*)d_in[0];
    const float* Wq = (const float*)d_in[3];
    const float* bq = (const float*)d_in[4];
    const float* Wk = (const float*)d_in[5];
    const float* bk = (const float*)d_in[6];
    const float* Wv = (const float*)d_in[7];
    const float* bv = (const float*)d_in[8];
    const float* Wo = (const float*)d_in[9];
    const float* bo = (const float*)d_in[10];

    char* ws = (char*)d_ws;
    constexpr size_t QKV_BYTES = (size_t)BH * L * HD * sizeof(bf16_t);  // 9437184
    constexpr size_t W_BYTES   = (size_t)E * E * sizeof(bf16_t);        // 2097152
    float*  tabs    = (float*)(ws);
    bf16_t* q_ws    = (bf16_t*)(ws + 16384);
    bf16_t* k_ws    = (bf16_t*)(ws + 16384 + 1 * QKV_BYTES);
    bf16_t* vT_ws   = (bf16_t*)(ws + 16384 + 2 * QKV_BYTES);
    bf16_t* attn_ws = (bf16_t*)(ws + 16384 + 3 * QKV_BYTES);
    bf16_t* Wq_b    = (bf16_t*)(ws + 16384 + 4 * QKV_BYTES);
    bf16_t* Wk_b    = (bf16_t*)(ws + 16384 + 4 * QKV_BYTES + 1 * W_BYTES);
    bf16_t* Wv_b    = (bf16_t*)(ws + 16384 + 4 * QKV_BYTES + 2 * W_BYTES);
    bf16_t* Wo_b    = (bf16_t*)(ws + 16384 + 4 * QKV_BYTES + 3 * W_BYTES);
    bf16_t* x_b     = (bf16_t*)(ws + 16384 + 4 * QKV_BYTES + 4 * W_BYTES);

    prep_kernel<<<T * E / 4 / 256, 256, 0, stream>>>(
        query, Wq, Wk, Wv, Wo, x_b, Wq_b, Wk_b, Wv_b, Wo_b, tabs);

    qkv_gemm_kernel<<<dim3(T / 128, E / 128, 3), 256, 0, stream>>>(
        x_b, Wq_b, Wk_b, Wv_b, bq, bk, bv, q_ws, k_ws, vT_ws, tabs);

    attn_kernel<<<576, 512, 0, stream>>>(q_ws, k_ws, vT_ws, attn_ws);

    out_gemm_kernel<<<dim3(T / 128, E / 64), 256, 0, stream>>>(attn_ws, Wo_b, bo, (float*)d_out);
}

// Round 18
// 145.314 us; speedup vs baseline: 1.0212x; 1.0212x over previous
//
#include <hip/hip_runtime.h>
#include <hip/hip_bf16.h>

typedef __bf16 bf16_t;
typedef __bf16 bf16x4 __attribute__((ext_vector_type(4)));
typedef __bf16 bf16x8 __attribute__((ext_vector_type(8)));
typedef float f32x4 __attribute__((ext_vector_type(4)));
typedef unsigned int u32;
typedef u32 u32x4 __attribute__((ext_vector_type(4)));

constexpr int E  = 1024;
constexpr int NH = 16;
constexpr int HD = 64;
constexpr int NB = 2;
constexpr int GS = 48;          // spatial side
constexpr int L  = GS * GS;     // 2304 tokens per batch
constexpr int T  = NB * L;      // 4608 tokens
constexpr int BH = NB * NH;     // 32 batch*head

static __device__ __forceinline__ float max3f(float a, float b, float c) {
    return fmaxf(fmaxf(a, b), c);   // clang fuses to v_max3_f32
}

static __device__ __forceinline__ void gload16(const void* g, void* l) {
    __builtin_amdgcn_global_load_lds(
        (const __attribute__((address_space(1))) unsigned int*)g,
        (__attribute__((address_space(3))) unsigned int*)l, 16, 0, 0);
}

// cross-half reduces via permlane-swap BUILTINS (hazards handled by compiler)
static __device__ __forceinline__ float redmax16(float x) {
    u32 a = __builtin_bit_cast(u32, x);
    auto r = __builtin_amdgcn_permlane16_swap(a, a, false, false);
    return fmaxf(__builtin_bit_cast(float, r[0]), __builtin_bit_cast(float, r[1]));
}
static __device__ __forceinline__ float redmax32(float x) {
    u32 a = __builtin_bit_cast(u32, x);
    auto r = __builtin_amdgcn_permlane32_swap(a, a, false, false);
    return fmaxf(__builtin_bit_cast(float, r[0]), __builtin_bit_cast(float, r[1]));
}
// single-instruction packed f32->bf16 (R7-proven; compiler scalar casts are multi-op)
static __device__ __forceinline__ u32 cvtpk(float lo, float hi) {
    u32 r;
    asm("v_cvt_pk_bf16_f32 %0, %1, %2" : "=v"(r) : "v"(lo), "v"(hi));
    return r;
}
// raw v_exp_f32 (2^x) via compiler-known builtin — no libcall range checks
static __device__ __forceinline__ float exp2fast(float x) {
    return __builtin_amdgcn_exp2f(x);
}

// ------- prep: cast x and Wq/Wk/Wv/Wo to bf16 (+ xpos tables in block 0) -------
__global__ __launch_bounds__(256)
void prep_kernel(const float* __restrict__ x,
                 const float* __restrict__ Wq, const float* __restrict__ Wk,
                 const float* __restrict__ Wv, const float* __restrict__ Wo,
                 bf16_t* __restrict__ x_b,
                 bf16_t* __restrict__ Wq_b, bf16_t* __restrict__ Wk_b,
                 bf16_t* __restrict__ Wv_b, bf16_t* __restrict__ Wo_b,
                 float* __restrict__ tabs)
{
    if (blockIdx.x == 0) {
        #pragma unroll
        for (int j = 0; j < 3; ++j) {
            int i = threadIdx.x + 256 * j;           // 0..767
            int p = i >> 4, jj = i & 15;
            float sv = (2.0f * (float)jj + 12.8f) / 44.8f;
            float pw = ((float)p - 24.0f) / 512.0f;
            float scale = powf(sv, pw);
            float inv_freq = powf(10000.0f, -(float)jj / 16.0f);
            float ang = (float)p * inv_freq;
            float s = sinf(ang), c = cosf(ang);
            tabs[0 * 768 + i] = c * scale;   // q: downscale=False
            tabs[1 * 768 + i] = s * scale;
            tabs[2 * 768 + i] = c / scale;   // k: downscale=True
            tabs[3 * 768 + i] = s / scale;
        }
    }
    const int gid = blockIdx.x * 256 + threadIdx.x;      // 0 .. T*E/4-1
    {
        f32x4 v = *reinterpret_cast<const f32x4*>(x + (size_t)gid * 4);
        bf16x4 o;
        o[0] = (bf16_t)v[0]; o[1] = (bf16_t)v[1]; o[2] = (bf16_t)v[2]; o[3] = (bf16_t)v[3];
        *reinterpret_cast<bf16x4*>(x_b + (size_t)gid * 4) = o;
    }
    if (blockIdx.x < 1024) {
        const float* srcs[4] = {Wq, Wk, Wv, Wo};
        bf16_t* dsts[4] = {Wq_b, Wk_b, Wv_b, Wo_b};
        #pragma unroll
        for (int wsel = 0; wsel < 4; ++wsel) {
            f32x4 v = *reinterpret_cast<const f32x4*>(srcs[wsel] + (size_t)gid * 4);
            bf16x4 o;
            o[0] = (bf16_t)v[0]; o[1] = (bf16_t)v[1]; o[2] = (bf16_t)v[2]; o[3] = (bf16_t)v[3];
            *reinterpret_cast<bf16x4*>(dsts[wsel] + (size_t)gid * 4) = o;
        }
    }
}

// ---------------- fused QKV GEMM (z = 0:Q+xpos, 1:K+xpos, 2:V transposed) ----------
// SM[0]=As, SM[1]=Bs during K-loop; reused as C-stage for coalesced Q/K stores.
__global__ __launch_bounds__(256, 3)
void qkv_gemm_kernel(const bf16_t* __restrict__ Ax,
                     const bf16_t* __restrict__ Wqb, const bf16_t* __restrict__ Wkb,
                     const bf16_t* __restrict__ Wvb,
                     const float* __restrict__ bq, const float* __restrict__ bk,
                     const float* __restrict__ bv,
                     bf16_t* __restrict__ q_ws, bf16_t* __restrict__ k_ws,
                     bf16_t* __restrict__ vT_ws, const float* __restrict__ tabs)
{
    __shared__ bf16_t SM[2][128 * 64];
    const int z = blockIdx.z;
    const bf16_t* Wb   = (z == 0) ? Wqb : (z == 1) ? Wkb : Wvb;
    const float*  bias = (z == 0) ? bq  : (z == 1) ? bk  : bv;

    const int tid = threadIdx.x;
    const int lane = tid & 63;
    const int wv = tid >> 6;
    const int wm = wv >> 1, wn = wv & 1;
    const int lr = lane & 15, lg = lane >> 4;
    const int bm = blockIdx.x, bn = blockIdx.y;

    f32x4 acc[4][4] = {};

    for (int kt = 0; kt < E / 64; ++kt) {
        const int k0 = kt * 64;
        __syncthreads();
        const bf16_t* Abase = Ax + (size_t)(bm * 128) * E + k0;
        const bf16_t* Wbase = Wb + (size_t)(bn * 128) * E + k0;
        #pragma unroll
        for (int it = 0; it < 4; ++it) {
            int s = it * 256 + tid;
            int r = s >> 3, c = s & 7;
            const int off = (c ^ (r & 7)) * 8;
            gload16(Abase + (size_t)r * E + off, (char*)SM[0] + it * 4096 + wv * 1024);
            gload16(Wbase + (size_t)r * E + off, (char*)SM[1] + it * 4096 + wv * 1024);
        }
        __syncthreads();
        #pragma unroll
        for (int kk = 0; kk < 2; ++kk) {
            bf16x8 af[4], bfr[4];
            #pragma unroll
            for (int m = 0; m < 4; ++m) {
                int row = wm * 64 + m * 16 + lr;
                af[m] = *reinterpret_cast<const bf16x8*>(&SM[0][row * 64 + (((kk * 4 + lg) ^ (row & 7)) * 8)]);
            }
            #pragma unroll
            for (int n = 0; n < 4; ++n) {
                int row = wn * 64 + n * 16 + lr;
                bfr[n] = *reinterpret_cast<const bf16x8*>(&SM[1][row * 64 + (((kk * 4 + lg) ^ (row & 7)) * 8)]);
            }
            #pragma unroll
            for (int m = 0; m < 4; ++m)
                #pragma unroll
                for (int n = 0; n < 4; ++n)
                    acc[m][n] = __builtin_amdgcn_mfma_f32_16x16x32_bf16(af[m], bfr[n], acc[m][n], 0, 0, 0);
        }
    }

    if (z < 2) {
        const float* cs_t = tabs + (z == 0 ? 0 : 1536);
        const float* ss_t = tabs + (z == 0 ? 768 : 2304);
        bf16_t* dst = (z == 0) ? q_ws : k_ws;
        // Q additionally scaled by log2(e) so attn softmax can use exp2 directly
        const float qscale = 0.125f * 1.44269504088896f;
        __syncthreads();   // all waves done reading SM as A/B
        #pragma unroll
        for (int m = 0; m < 4; ++m) {
            #pragma unroll
            for (int n = 0; n < 4; ++n) {
                const int col = bn * 128 + wn * 64 + n * 16 + lr;
                const float bvv = bias[col];
                const int d = col & 63;
                const int j = (d & 31) >> 1, half = d >> 5, odd = d & 1;
                #pragma unroll
                for (int r = 0; r < 4; ++r) {
                    const int rowl = wm * 64 + m * 16 + lg * 4 + r;
                    const int rowg = bm * 128 + rowl;
                    const int nb = rowg / L, ll = rowg - nb * L;
                    const int y = ll / GS, x = ll - y * GS;
                    const int pos = half ? y : x;
                    float v = acc[m][n][r] + bvv;
                    if (z == 0) v *= qscale;
                    float o = __shfl_xor(v, 1);
                    float cs = cs_t[pos * 16 + j], ss = ss_t[pos * 16 + j];
                    float res = odd ? (v * cs + o * ss) : (v * cs - o * ss);
                    SM[wn][rowl * 64 + n * 16 + lr] = (bf16_t)res;
                }
            }
        }
        __syncthreads();
        const int row = tid >> 1;
        const int off32 = (tid & 1) * 32;
        const int rowg = bm * 128 + row;
        const int nb2 = (rowg >= L) ? 1 : 0;
        const int ll = rowg - nb2 * L;
        #pragma unroll
        for (int phase = 0; phase < 2; ++phase) {
            const int head = bn * 2 + phase;
            bf16_t* gdst = dst + ((size_t)(nb2 * NH + head) * L + ll) * HD + off32;
            const bf16_t* src = &SM[phase][row * 64 + off32];
            #pragma unroll
            for (int c = 0; c < 4; ++c)
                *reinterpret_cast<bf16x8*>(gdst + c * 8) =
                    *reinterpret_cast<const bf16x8*>(src + c * 8);
        }
    } else {
        #pragma unroll
        for (int m = 0; m < 4; ++m) {
            const int rowg0 = bm * 128 + wm * 64 + m * 16 + lg * 4;
            const int nb = rowg0 / L, ll0 = rowg0 - nb * L;
            #pragma unroll
            for (int n = 0; n < 4; ++n) {
                const int col = bn * 128 + wn * 64 + n * 16 + lr;
                const float bvv = bias[col];
                const int head = col >> 6, d = col & 63;
                bf16x4 pk;
                #pragma unroll
                for (int r = 0; r < 4; ++r) pk[r] = (bf16_t)(acc[m][n][r] + bvv);
                *reinterpret_cast<bf16x4*>(&vT_ws[((size_t)(nb * NH + head) * HD + d) * L + ll0]) = pk;
            }
        }
    }
}

// ---------------- flash attention: 16q/wave, LDS dbuf, XCD-swizzled blocks --------
// grid 1152 (1D); swz = (n&7)*144 + (n>>3) pins 4 bh (2.3MB K+V) per XCD -> L2-fit.
// LDS 32KB -> 5 blocks/CU = 160KB exactly.
__global__ __launch_bounds__(256, 5)
void attn_kernel(const bf16_t* __restrict__ q_ws, const bf16_t* __restrict__ k_ws,
                 const bf16_t* __restrict__ vT_ws, bf16_t* __restrict__ attn_out)
{
    __shared__ bf16_t K_lds[2][64 * 64];   // [l][d], chunk-XOR-swizzled rows (128B)
    __shared__ bf16_t V_lds[2][64 * 64];   // [d][l], chunk-XOR-swizzled rows (128B)
    const int tid = threadIdx.x;
    const int lane = tid & 63, w = tid >> 6;
    const int lr = lane & 15, lg = lane >> 4;
    // XCD-aware bijective swizzle: 1152 = 8 * 144; chunk of 144 = 4 bh -> one XCD
    const int n = blockIdx.x;
    const int swz = (n & 7) * 144 + (n >> 3);
    const int bh = swz / 36;
    const int q0 = (swz - bh * 36) * 64 + w * 16;
    const int nb = bh >> 4, head = bh & 15;

    const bf16_t* qb = q_ws + (size_t)bh * L * HD;
    const bf16_t* kb = k_ws + (size_t)bh * L * HD;
    const bf16_t* vb = vT_ws + (size_t)bh * HD * L;

    const int s0 = w * 128 + lane;
    const int r0 = s0 >> 3, c0 = s0 & 7;
    const int cx = c0 ^ (r0 & 7);
    const bf16_t* kst = kb + r0 * HD + cx * 8;
    const bf16_t* vst = vb + (size_t)r0 * L + cx * 8;

    bf16x8 qf[2];
    qf[0] = *reinterpret_cast<const bf16x8*>(qb + (size_t)(q0 + lr) * HD + lg * 8);
    qf[1] = *reinterpret_cast<const bf16x8*>(qb + (size_t)(q0 + lr) * HD + 32 + lg * 8);

    // ones A-fragment: l_acc = mfma(ones, P, l_acc) accumulates column sums of P
    bf16x8 ones;
    #pragma unroll
    for (int i = 0; i < 8; ++i) ones[i] = (bf16_t)1.0f;

    // hoisted lane-constant LDS element offsets (independent of kt/BUF)
    int koffA[4], koffB[4], voff[2][4];
    #pragma unroll
    for (int ct = 0; ct < 4; ++ct) {
        const int row = ct * 16 + lr;
        koffA[ct] = row * 64 + ((lg ^ (lr & 7)) * 8);
        koffB[ct] = row * 64 + (((4 + lg) ^ (lr & 7)) * 8);
    }
    #pragma unroll
    for (int kk = 0; kk < 2; ++kk)
        #pragma unroll
        for (int dt = 0; dt < 4; ++dt)
            voff[kk][dt] = (dt * 16 + lr) * 64 + (((kk * 4 + lg) ^ (lr & 7)) * 8);

    f32x4 o_acc[4] = {};
    f32x4 l_acc = {};
    float m_run = -1e30f;

    // stage tile 0 -> buf 0
    gload16(kst,         &K_lds[0][w * 1024]);
    gload16(kst + 512,   &K_lds[0][w * 1024 + 512]);
    gload16(vst,         &V_lds[0][w * 1024]);
    gload16(vst + 8 * L, &V_lds[0][w * 1024 + 512]);
    __syncthreads();

    // incremental prefetch pointers (advance by 2 tiles per loop iteration)
    const bf16_t* kpA = kst + 4096;   const bf16_t* vpA = vst + 64;    // odd tiles
    const bf16_t* kpB = kst + 8192;   const bf16_t* vpB = vst + 128;   // even tiles

    constexpr int NT = L / 64;   // 36 (even)

#define ATTN_COMPUTE(BUF)                                                              \
    {                                                                                  \
        f32x4 s[4];                                                                    \
        __builtin_amdgcn_s_setprio(1);                                                 \
        _Pragma("unroll")                                                              \
        for (int ct = 0; ct < 4; ++ct) {                                               \
            bf16x8 kf0 = *reinterpret_cast<const bf16x8*>(&K_lds[BUF][koffA[ct]]);     \
            bf16x8 kf1 = *reinterpret_cast<const bf16x8*>(&K_lds[BUF][koffB[ct]]);     \
            f32x4 t = {};                                                              \
            t = __builtin_amdgcn_mfma_f32_16x16x32_bf16(kf0, qf[0], t, 0, 0, 0);       \
            t = __builtin_amdgcn_mfma_f32_16x16x32_bf16(kf1, qf[1], t, 0, 0, 0);       \
            s[ct] = t;                                                                 \
        }                                                                              \
        __builtin_amdgcn_s_setprio(0);                                                 \
        float m0 = max3f(s[0][0], s[0][1], s[0][2]);                                   \
        float m1 = max3f(s[0][3], s[1][0], s[1][1]);                                   \
        float m2 = max3f(s[1][2], s[1][3], s[2][0]);                                   \
        float m3 = max3f(s[2][1], s[2][2], s[2][3]);                                   \
        float m4 = max3f(s[3][0], s[3][1], s[3][2]);                                   \
        float mt = fmaxf(max3f(m0, m1, m2), max3f(m3, m4, s[3][3]));                   \
        mt = redmax16(mt);                                                             \
        mt = redmax32(mt);                                                             \
        if (!__all(mt <= m_run + 11.54f)) {                                            \
            const float mn = fmaxf(m_run, mt);                                         \
            const float al = exp2fast(m_run - mn);                                     \
            m_run = mn;                                                                \
            l_acc *= al;                                                               \
            _Pragma("unroll")                                                          \
            for (int dt = 0; dt < 4; ++dt) o_acc[dt] *= al;                            \
        }                                                                              \
        _Pragma("unroll")                                                              \
        for (int ct = 0; ct < 4; ++ct) {                                               \
            s[ct][0] = exp2fast(s[ct][0] - m_run); s[ct][1] = exp2fast(s[ct][1] - m_run); \
            s[ct][2] = exp2fast(s[ct][2] - m_run); s[ct][3] = exp2fast(s[ct][3] - m_run); \
        }                                                                              \
        u32 c01[4], c23[4];                                                            \
        _Pragma("unroll")                                                              \
        for (int ct = 0; ct < 4; ++ct) {                                               \
            c01[ct] = cvtpk(s[ct][0], s[ct][1]);                                       \
            c23[ct] = cvtpk(s[ct][2], s[ct][3]);                                       \
        }                                                                              \
        __builtin_amdgcn_s_setprio(1);                                                 \
        _Pragma("unroll")                                                              \
        for (int kk = 0; kk < 2; ++kk) {                                               \
            auto p1 = __builtin_amdgcn_permlane32_swap(c01[kk*2], c01[kk*2+1], false, false); \
            auto p2 = __builtin_amdgcn_permlane16_swap(p1[0], p1[1], false, false);    \
            auto p3 = __builtin_amdgcn_permlane32_swap(c23[kk*2], c23[kk*2+1], false, false); \
            auto p4 = __builtin_amdgcn_permlane16_swap(p3[0], p3[1], false, false);    \
            u32x4 paw;                                                                 \
            paw[0] = p2[0]; paw[1] = p4[0]; paw[2] = p2[1]; paw[3] = p4[1];            \
            bf16x8 pa = __builtin_bit_cast(bf16x8, paw);                               \
            l_acc = __builtin_amdgcn_mfma_f32_16x16x32_bf16(ones, pa, l_acc, 0, 0, 0); \
            _Pragma("unroll")                                                          \
            for (int dt = 0; dt < 4; ++dt) {                                           \
                bf16x8 vfr = *reinterpret_cast<const bf16x8*>(&V_lds[BUF][voff[kk][dt]]); \
                o_acc[dt] = __builtin_amdgcn_mfma_f32_16x16x32_bf16(vfr, pa, o_acc[dt], 0, 0, 0); \
            }                                                                          \
        }                                                                              \
        __builtin_amdgcn_s_setprio(0);                                                 \
        __syncthreads();                                                               \
    }

    for (int it = 0; it < NT / 2; ++it) {
        // even tile 2*it: compute buf0; prefetch tile 2*it+1 -> buf1 (always valid)
        gload16(kpA,         &K_lds[1][w * 1024]);
        gload16(kpA + 512,   &K_lds[1][w * 1024 + 512]);
        gload16(vpA,         &V_lds[1][w * 1024]);
        gload16(vpA + 8 * L, &V_lds[1][w * 1024 + 512]);
        kpA += 8192; vpA += 128;
        ATTN_COMPUTE(0)
        // odd tile 2*it+1: compute buf1; prefetch tile 2*it+2 -> buf0 (if exists)
        if (it < NT / 2 - 1) {
            gload16(kpB,         &K_lds[0][w * 1024]);
            gload16(kpB + 512,   &K_lds[0][w * 1024 + 512]);
            gload16(vpB,         &V_lds[0][w * 1024]);
            gload16(vpB + 8 * L, &V_lds[0][w * 1024 + 512]);
            kpB += 8192; vpB += 128;
        }
        ATTN_COMPUTE(1)
    }
#undef ATTN_COMPUTE

    const float inv = 1.0f / l_acc[0];
    #pragma unroll
    for (int dt = 0; dt < 4; ++dt) {
        bf16x4 o;
        #pragma unroll
        for (int r = 0; r < 4; ++r) o[r] = (bf16_t)(o_acc[dt][r] * inv);
        *reinterpret_cast<bf16x4*>(
            &attn_out[(size_t)(nb * L + q0 + lr) * E + head * HD + dt * 16 + lg * 4]) = o;
    }
}

// ---------------- output projection GEMM: 128x64 tiles (2.25 blocks/CU) -----------
__global__ __launch_bounds__(256, 4)
void out_gemm_kernel(const bf16_t* __restrict__ A, const bf16_t* __restrict__ Wb,
                     const float* __restrict__ bias, float* __restrict__ outp)
{
    __shared__ bf16_t As[128 * 64];
    __shared__ bf16_t Bs[64 * 64];
    const int tid = threadIdx.x;
    const int lane = tid & 63;
    const int wv = tid >> 6;
    const int wm = wv >> 1, wn = wv & 1;
    const int lr = lane & 15, lg = lane >> 4;
    const int bm = blockIdx.x, bn = blockIdx.y;

    f32x4 acc[4][2] = {};

    for (int kt = 0; kt < E / 64; ++kt) {
        const int k0 = kt * 64;
        __syncthreads();
        const bf16_t* Abase = A  + (size_t)(bm * 128) * E + k0;
        const bf16_t* Wbase = Wb + (size_t)(bn * 64) * E + k0;
        #pragma unroll
        for (int it = 0; it < 4; ++it) {
            int s = it * 256 + tid;
            int r = s >> 3, c = s & 7;
            const int off = (c ^ (r & 7)) * 8;
            gload16(Abase + (size_t)r * E + off, (char*)As + it * 4096 + wv * 1024);
        }
        #pragma unroll
        for (int it = 0; it < 2; ++it) {
            int s = it * 256 + tid;
            int r = s >> 3, c = s & 7;
            const int off = (c ^ (r & 7)) * 8;
            gload16(Wbase + (size_t)r * E + off, (char*)Bs + it * 4096 + wv * 1024);
        }
        __syncthreads();
        #pragma unroll
        for (int kk = 0; kk < 2; ++kk) {
            bf16x8 af[4], bfr[2];
            #pragma unroll
            for (int m = 0; m < 4; ++m) {
                int row = wm * 64 + m * 16 + lr;
                af[m] = *reinterpret_cast<const bf16x8*>(&As[row * 64 + (((kk * 4 + lg) ^ (row & 7)) * 8)]);
            }
            #pragma unroll
            for (int n = 0; n < 2; ++n) {
                int row = wn * 32 + n * 16 + lr;
                bfr[n] = *reinterpret_cast<const bf16x8*>(&Bs[row * 64 + (((kk * 4 + lg) ^ (row & 7)) * 8)]);
            }
            #pragma unroll
            for (int m = 0; m < 4; ++m)
                #pragma unroll
                for (int n = 0; n < 2; ++n)
                    acc[m][n] = __builtin_amdgcn_mfma_f32_16x16x32_bf16(af[m], bfr[n], acc[m][n], 0, 0, 0);
        }
    }

    #pragma unroll
    for (int m = 0; m < 4; ++m) {
        #pragma unroll
        for (int n = 0; n < 2; ++n) {
            const int col = bn * 64 + wn * 32 + n * 16 + lr;
            const float bvv = bias[col];
            #pragma unroll
            for (int r = 0; r < 4; ++r) {
                const int rowg = bm * 128 + wm * 64 + m * 16 + lg * 4 + r;
                outp[(size_t)rowg * E + col] = acc[m][n][r] + bvv;
            }
        }
    }
}

// ---------------- launch ----------------
extern "C" void kernel_launch(void* const* d_in, const int* in_sizes, int n_in,
                              void* d_out, int out_size, void* d_ws, size_t ws_size,
                              hipStream_t stream)
{
    const float* query = (const float*)d_in[0];
    const float* Wq = (const float*)d_in[3];
    const float* bq = (const float*)d_in[4];
    const float* Wk = (const float*)d_in[5];
    const float* bk = (const float*)d_in[6];
    const float* Wv = (const float*)d_in[7];
    const float* bv = (const float*)d_in[8];
    const float* Wo = (const float*)d_in[9];
    const float* bo = (const float*)d_in[10];

    char* ws = (char*)d_ws;
    constexpr size_t QKV_BYTES = (size_t)BH * L * HD * sizeof(bf16_t);  // 9437184
    constexpr size_t W_BYTES   = (size_t)E * E * sizeof(bf16_t);        // 2097152
    float*  tabs    = (float*)(ws);
    bf16_t* q_ws    = (bf16_t*)(ws + 16384);
    bf16_t* k_ws    = (bf16_t*)(ws + 16384 + 1 * QKV_BYTES);
    bf16_t* vT_ws   = (bf16_t*)(ws + 16384 + 2 * QKV_BYTES);
    bf16_t* attn_ws = (bf16_t*)(ws + 16384 + 3 * QKV_BYTES);
    bf16_t* Wq_b    = (bf16_t*)(ws + 16384 + 4 * QKV_BYTES);
    bf16_t* Wk_b    = (bf16_t*)(ws + 16384 + 4 * QKV_BYTES + 1 * W_BYTES);
    bf16_t* Wv_b    = (bf16_t*)(ws + 16384 + 4 * QKV_BYTES + 2 * W_BYTES);
    bf16_t* Wo_b    = (bf16_t*)(ws + 16384 + 4 * QKV_BYTES + 3 * W_BYTES);
    bf16_t* x_b     = (bf16_t*)(ws + 16384 + 4 * QKV_BYTES + 4 * W_BYTES);

    prep_kernel<<<T * E / 4 / 256, 256, 0, stream>>>(
        query, Wq, Wk, Wv, Wo, x_b, Wq_b, Wk_b, Wv_b, Wo_b, tabs);

    qkv_gemm_kernel<<<dim3(T / 128, E / 128, 3), 256, 0, stream>>>(
        x_b, Wq_b, Wk_b, Wv_b, bq, bk, bv, q_ws, k_ws, vT_ws, tabs);

    attn_kernel<<<1152, 256, 0, stream>>>(q_ws, k_ws, vT_ws, attn_ws);

    out_gemm_kernel<<<dim3(T / 128, E / 64), 256, 0, stream>>>(attn_ws, Wo_b, bo, (float*)d_out);
}